// Round 4
// baseline (387.721 us; speedup 1.0000x reference)
//
#include <hip/hip_runtime.h>
#include <hip/hip_bf16.h>
#include <stdint.h>

#define B_ 8
#define S_ 2048
#define E_ 768

typedef __attribute__((ext_vector_type(4))) float f32x4;
typedef __attribute__((ext_vector_type(8))) short bf16x8;

// Pipelined GEMM core geometry: BM=256, BK=64, 512 thr (8 waves 4Mx2N)
#define A_TILE_USH (256 * 64)  // 32 KB

__device__ __forceinline__ unsigned pk2bf(float x, float y) {
  unsigned r;
  asm("v_cvt_pk_bf16_f32 %0, %1, %2" : "=v"(r) : "v"(x), "v"(y));
  return r;
}

__device__ __forceinline__ void gll16(const void* g, void* l) {
  __builtin_amdgcn_global_load_lds((const __attribute__((address_space(1))) void*)g,
                                   (__attribute__((address_space(3))) void*)l, 16, 0, 0);
}

// Stage K-tile kt (A: 256x64 bf16, B: BROWSx64 bf16) via global_load_lds.
// LDS dest linear; global SOURCE pre-swizzled with the reader's XOR (rule #21).
template <int BROWS>
__device__ __forceinline__ void stage_tile(const char* Ab, const char* Bb,
                                           int ldAb, int ldBb, int kt,
                                           unsigned short* As, unsigned short* Bs, int tid) {
#pragma unroll
  for (int i = 0; i < 4; ++i) {
    const unsigned lin = (unsigned)i * 8192u + (unsigned)tid * 16u;
    const unsigned row = lin >> 7, cb = lin & 127u;
    const unsigned cbs = cb ^ ((row & 7u) << 4);
    gll16(Ab + (size_t)row * ldAb + (size_t)kt * 128 + cbs, (char*)As + lin);
  }
#pragma unroll
  for (int i = 0; i < BROWS / 64; ++i) {
    const unsigned lin = (unsigned)i * 8192u + (unsigned)tid * 16u;
    const unsigned row = lin >> 7, cb = lin & 127u;
    const unsigned cbs = cb ^ ((row & 7u) << 4);
    gll16(Bb + (size_t)row * ldBb + (size_t)kt * 128 + cbs, (char*)Bs + lin);
  }
}

template <int NACC>
__device__ __forceinline__ void compute_tile(const unsigned short* As, const unsigned short* Bs,
                                             int wm, int wn, int lane, f32x4 (&acc)[4][NACC]) {
  bf16x8 af[4][2], bv[NACC][2];
#pragma unroll
  for (int m = 0; m < 4; ++m) {
    const int row = wm * 64 + m * 16 + (lane & 15);
#pragma unroll
    for (int ks = 0; ks < 2; ++ks) {
      const unsigned cb = ((unsigned)ks * 64u + (unsigned)(lane >> 4) * 16u) ^ (((unsigned)row & 7u) << 4);
      af[m][ks] = *reinterpret_cast<const bf16x8*>((const char*)As + row * 128 + cb);
    }
  }
#pragma unroll
  for (int n = 0; n < NACC; ++n) {
    const int row = wn * (NACC * 16) + n * 16 + (lane & 15);
#pragma unroll
    for (int ks = 0; ks < 2; ++ks) {
      const unsigned cb = ((unsigned)ks * 64u + (unsigned)(lane >> 4) * 16u) ^ (((unsigned)row & 7u) << 4);
      bv[n][ks] = *reinterpret_cast<const bf16x8*>((const char*)Bs + row * 128 + cb);
    }
  }
  __builtin_amdgcn_s_setprio(1);
#pragma unroll
  for (int ks = 0; ks < 2; ++ks)
#pragma unroll
    for (int m = 0; m < 4; ++m)
#pragma unroll
      for (int n = 0; n < NACC; ++n)
        acc[m][n] = __builtin_amdgcn_mfma_f32_16x16x32_bf16(af[m][ks], bv[n][ks], acc[m][n], 0, 0, 0);
  __builtin_amdgcn_s_setprio(0);
}

// 3-stage pipeline, one barrier per K-tile, counted vmcnt (= loads/tile).
template <int BROWS, int NACC>
__device__ __forceinline__ void gemm_pipe(const char* Ab, const char* Bb, int ldAb, int ldBb,
                                          int NT, unsigned short* AsAll, unsigned short* BsAll,
                                          int tid, int wm, int wn, int lane,
                                          f32x4 (&acc)[4][NACC]) {
  constexpr int BT = BROWS * 64;
  constexpr int L = 4 + BROWS / 64;
  stage_tile<BROWS>(Ab, Bb, ldAb, ldBb, 0, AsAll, BsAll, tid);
  stage_tile<BROWS>(Ab, Bb, ldAb, ldBb, 1, AsAll + A_TILE_USH, BsAll + BT, tid);
  if constexpr (L == 6) asm volatile("s_waitcnt vmcnt(6)" ::: "memory");
  else                  asm volatile("s_waitcnt vmcnt(5)" ::: "memory");
  __builtin_amdgcn_s_barrier();
  __builtin_amdgcn_sched_barrier(0);
  for (int kt = 0; kt < NT; ++kt) {
    const int bk = kt % 3;
    if (kt + 2 < NT) {
      const int bs = (kt + 2) % 3;
      stage_tile<BROWS>(Ab, Bb, ldAb, ldBb, kt + 2, AsAll + bs * A_TILE_USH, BsAll + bs * BT, tid);
    }
    compute_tile<NACC>(AsAll + bk * A_TILE_USH, BsAll + bk * BT, wm, wn, lane, acc);
    if (kt + 1 < NT) {
      if (kt + 2 < NT) {
        if constexpr (L == 6) asm volatile("s_waitcnt vmcnt(6) lgkmcnt(0)" ::: "memory");
        else                  asm volatile("s_waitcnt vmcnt(5) lgkmcnt(0)" ::: "memory");
      } else {
        asm volatile("s_waitcnt vmcnt(0) lgkmcnt(0)" ::: "memory");
      }
      __builtin_amdgcn_s_barrier();
      __builtin_amdgcn_sched_barrier(0);
    }
  }
}

// ---------------- K1: projection GEMM  O = X @ W^T + b  (f32 in, bf16 out) ----------
// Pipelined reg-staged conversion: loads f32 tile t+1 early, MFMA tile t, then
// cvt_pk + ds_write after vmcnt(0); one barrier per K-tile, 2 LDS buffers.
__global__ __launch_bounds__(512, 2) void k_proj(const float* __restrict__ qin,
                                                 const float* __restrict__ kin,
                                                 const float* __restrict__ vin,
                                                 const float* __restrict__ W,
                                                 const float* __restrict__ bias,
                                                 unsigned short* __restrict__ qp,
                                                 unsigned short* __restrict__ kp,
                                                 unsigned short* __restrict__ vp) {
  __shared__ __attribute__((aligned(16))) unsigned short As[2][256 * 64];  // 2x32 KB
  __shared__ __attribute__((aligned(16))) unsigned short Bs[2][128 * 64];  // 2x16 KB
  const int tid = threadIdx.x, lane = tid & 63, wid = tid >> 6;
  const int wm = wid >> 1, wn = wid & 1;
  const int bx = blockIdx.x;                  // 0..191 (64 row-tiles per tensor)
  const int z = bx >> 6;
  const int r0 = (bx & 63) * 256;
  const int c0 = blockIdx.y * 128;
  const float* X = (z == 0) ? qin : ((z == 1) ? kin : vin);
  unsigned short* O = (z == 0) ? qp : ((z == 1) ? kp : vp);

  f32x4 acc[4][4] = {};
  float4 ra[8], rb[4];
  const int NT = E_ / 64;  // 12

  // prologue: tile 0
#pragma unroll
  for (int i = 0; i < 8; ++i) {
    int idx = i * 512 + tid;
    ra[i] = *reinterpret_cast<const float4*>(&X[(size_t)(r0 + (idx >> 4)) * E_ + (idx & 15) * 4]);
  }
#pragma unroll
  for (int i = 0; i < 4; ++i) {
    int idx = i * 512 + tid;
    rb[i] = *reinterpret_cast<const float4*>(&W[(size_t)(c0 + (idx >> 4)) * E_ + (idx & 15) * 4]);
  }
  asm volatile("s_waitcnt vmcnt(0)" ::: "memory");
#pragma unroll
  for (int i = 0; i < 8; ++i) {
    int idx = i * 512 + tid, row = idx >> 4, c4 = idx & 15;
    uint2 p;
    p.x = pk2bf(ra[i].x, ra[i].y);
    p.y = pk2bf(ra[i].z, ra[i].w);
    unsigned off = ((unsigned)(row * 128 + c4 * 8)) ^ (((unsigned)row & 7u) << 4);
    *reinterpret_cast<uint2*>((char*)As[0] + off) = p;
  }
#pragma unroll
  for (int i = 0; i < 4; ++i) {
    int idx = i * 512 + tid, row = idx >> 4, c4 = idx & 15;
    uint2 p;
    p.x = pk2bf(rb[i].x, rb[i].y);
    p.y = pk2bf(rb[i].z, rb[i].w);
    unsigned off = ((unsigned)(row * 128 + c4 * 8)) ^ (((unsigned)row & 7u) << 4);
    *reinterpret_cast<uint2*>((char*)Bs[0] + off) = p;
  }
  asm volatile("s_waitcnt lgkmcnt(0)" ::: "memory");
  __builtin_amdgcn_s_barrier();
  __builtin_amdgcn_sched_barrier(0);

  for (int kt = 0; kt < NT; ++kt) {
    if (kt + 1 < NT) {
      const int kc = (kt + 1) * 64;
#pragma unroll
      for (int i = 0; i < 8; ++i) {
        int idx = i * 512 + tid;
        ra[i] = *reinterpret_cast<const float4*>(
            &X[(size_t)(r0 + (idx >> 4)) * E_ + kc + (idx & 15) * 4]);
      }
#pragma unroll
      for (int i = 0; i < 4; ++i) {
        int idx = i * 512 + tid;
        rb[i] = *reinterpret_cast<const float4*>(
            &W[(size_t)(c0 + (idx >> 4)) * E_ + kc + (idx & 15) * 4]);
      }
    }
    __builtin_amdgcn_sched_barrier(0);
    compute_tile<4>(As[kt & 1], Bs[kt & 1], wm, wn, lane, acc);
    if (kt + 1 < NT) {
      const int nb = (kt + 1) & 1;
      asm volatile("s_waitcnt vmcnt(0)" ::: "memory");
#pragma unroll
      for (int i = 0; i < 8; ++i) {
        int idx = i * 512 + tid, row = idx >> 4, c4 = idx & 15;
        uint2 p;
        p.x = pk2bf(ra[i].x, ra[i].y);
        p.y = pk2bf(ra[i].z, ra[i].w);
        unsigned off = ((unsigned)(row * 128 + c4 * 8)) ^ (((unsigned)row & 7u) << 4);
        *reinterpret_cast<uint2*>((char*)As[nb] + off) = p;
      }
#pragma unroll
      for (int i = 0; i < 4; ++i) {
        int idx = i * 512 + tid, row = idx >> 4, c4 = idx & 15;
        uint2 p;
        p.x = pk2bf(rb[i].x, rb[i].y);
        p.y = pk2bf(rb[i].z, rb[i].w);
        unsigned off = ((unsigned)(row * 128 + c4 * 8)) ^ (((unsigned)row & 7u) << 4);
        *reinterpret_cast<uint2*>((char*)Bs[nb] + off) = p;
      }
      asm volatile("s_waitcnt lgkmcnt(0)" ::: "memory");
      __builtin_amdgcn_s_barrier();
      __builtin_amdgcn_sched_barrier(0);
    }
  }

  // epilogue: bias add, pack pairs, store bf16
  float bcol[4];
#pragma unroll
  for (int n = 0; n < 4; ++n) bcol[n] = bias[c0 + wn * 64 + n * 16 + (lane & 15)];
#pragma unroll
  for (int m = 0; m < 4; ++m)
#pragma unroll
    for (int r = 0; r < 4; ++r) {
      const int row = r0 + wm * 64 + m * 16 + (lane >> 4) * 4 + r;
      const int colb = c0 + wn * 64 + (lane & 15);
      unsigned pkA = pk2bf(acc[m][0][r] + bcol[0], acc[m][1][r] + bcol[1]);
      unsigned pkB = pk2bf(acc[m][2][r] + bcol[2], acc[m][3][r] + bcol[3]);
      O[(size_t)row * E_ + colb]      = (unsigned short)pkA;
      O[(size_t)row * E_ + colb + 16] = (unsigned short)(pkA >> 16);
      O[(size_t)row * E_ + colb + 32] = (unsigned short)pkB;
      O[(size_t)row * E_ + colb + 48] = (unsigned short)(pkB >> 16);
    }
}

// ---------------- K1b: transpose vp [B*S][E] -> vpT [B][E][S] ------------------------
__global__ __launch_bounds__(256) void k_vtrans(const unsigned short* __restrict__ vp,
                                                unsigned short* __restrict__ vpT) {
  __shared__ __attribute__((aligned(16))) unsigned short t[64][72];
  const int tid = threadIdx.x;
  const int st = blockIdx.x;
  const int ot = blockIdx.y;
  const int b = blockIdx.z;
#pragma unroll
  for (int i = 0; i < 2; ++i) {
    int f = i * 256 + tid;
    int s = f >> 3, c8 = f & 7;
    uint4 vv = *reinterpret_cast<const uint4*>(
        &vp[((size_t)b * S_ + st * 64 + s) * E_ + ot * 64 + c8 * 8]);
    *reinterpret_cast<uint4*>(&t[s][c8 * 8]) = vv;
  }
  __syncthreads();
  const int o = tid >> 2;
  const int sb = (tid & 3) * 16;
  unsigned p[8];
#pragma unroll
  for (int j = 0; j < 8; ++j)
    p[j] = (unsigned)t[sb + 2 * j][o] | ((unsigned)t[sb + 2 * j + 1][o] << 16);
  uint4 w0 = make_uint4(p[0], p[1], p[2], p[3]);
  uint4 w1 = make_uint4(p[4], p[5], p[6], p[7]);
  size_t ob = ((size_t)b * E_ + ot * 64 + o) * S_ + st * 64 + sb;
  *reinterpret_cast<uint4*>(&vpT[ob]) = w0;
  *reinterpret_cast<uint4*>(&vpT[ob + 8]) = w1;
}

// ---------------- K2: scores tile GEMM + mask + exp (unnormalized) + rowsum ---------
__global__ __launch_bounds__(512, 2) void k_scores(const unsigned short* __restrict__ qp,
                                                   const unsigned short* __restrict__ kp,
                                                   const int* __restrict__ mask,
                                                   unsigned short* __restrict__ P,
                                                   float* __restrict__ rowsum) {
  __shared__ __attribute__((aligned(16))) unsigned short AsAll[3 * A_TILE_USH];  // 96 KB
  __shared__ __attribute__((aligned(16))) unsigned short BsAll[3 * 128 * 64];    // 48 KB
  __shared__ float rlds[256][2];
  const int tid = threadIdx.x, lane = tid & 63, wid = tid >> 6;
  const int wm = wid >> 1, wn = wid & 1;
  const int qt = blockIdx.x, yt = blockIdx.y, b = blockIdx.z;
  const char* Ab = (const char*)(qp + ((size_t)b * S_ + qt * 256) * E_);
  const char* Bb = (const char*)(kp + ((size_t)b * S_ + yt * 128) * E_);
  f32x4 acc[4][4] = {};
  gemm_pipe<128, 4>(Ab, Bb, E_ * 2, E_ * 2, E_ / 64, AsAll, BsAll, tid, wm, wn, lane, acc);

  const float SC = (float)(1.4426950408889634 / 27.712812921102035);  // log2(e)/sqrt(768)
  float rs[4][4];
#pragma unroll
  for (int m = 0; m < 4; ++m)
#pragma unroll
    for (int r = 0; r < 4; ++r) {
      const int grow = qt * 256 + wm * 64 + m * 16 + (lane >> 4) * 4 + r;
      const size_t rowoff = ((size_t)b * S_ + grow) * S_;
      const int cbase = yt * 128 + wn * 64 + (lane & 15);
      const int mk0 = mask[rowoff + cbase];
      const int mk1 = mask[rowoff + cbase + 16];
      const int mk2 = mask[rowoff + cbase + 32];
      const int mk3 = mask[rowoff + cbase + 48];
      float p0 = (mk0 == 1) ? 0.f : __builtin_amdgcn_exp2f(acc[m][0][r] * SC);
      float p1 = (mk1 == 1) ? 0.f : __builtin_amdgcn_exp2f(acc[m][1][r] * SC);
      float p2 = (mk2 == 1) ? 0.f : __builtin_amdgcn_exp2f(acc[m][2][r] * SC);
      float p3 = (mk3 == 1) ? 0.f : __builtin_amdgcn_exp2f(acc[m][3][r] * SC);
      unsigned pkA = pk2bf(p0, p1);
      unsigned pkB = pk2bf(p2, p3);
      P[rowoff + cbase]      = (unsigned short)pkA;
      P[rowoff + cbase + 16] = (unsigned short)(pkA >> 16);
      P[rowoff + cbase + 32] = (unsigned short)pkB;
      P[rowoff + cbase + 48] = (unsigned short)(pkB >> 16);
      rs[m][r] = (p0 + p1) + (p2 + p3);
    }

#pragma unroll
  for (int m = 0; m < 4; ++m)
#pragma unroll
    for (int r = 0; r < 4; ++r) {
      float vsum = rs[m][r];
      vsum += __shfl_xor(vsum, 1);
      vsum += __shfl_xor(vsum, 2);
      vsum += __shfl_xor(vsum, 4);
      vsum += __shfl_xor(vsum, 8);
      if ((lane & 15) == 0) rlds[wm * 64 + m * 16 + (lane >> 4) * 4 + r][wn] = vsum;
    }
  __syncthreads();
  if (tid < 256) {
    rowsum[(size_t)yt * (B_ * S_) + (size_t)b * S_ + qt * 256 + tid] =
        rlds[tid][0] + rlds[tid][1];
  }
}

// ---------------- K2b: inv_rs = 1 / sum_yt rowsum -----------------------------------
__global__ __launch_bounds__(256) void k_invrs(const float* __restrict__ rowsum,
                                               float* __restrict__ inv_rs) {
  int i = blockIdx.x * 256 + threadIdx.x;
  float t = 0.f;
#pragma unroll
  for (int g = 0; g < 16; ++g) t += rowsum[(size_t)g * (B_ * S_) + i];
  inv_rs[i] = 1.0f / t;
}

// ---------------- K3: out = (P @ vpT^T) * inv_rs  (f32 out), BN=64 ------------------
__global__ __launch_bounds__(512, 2) void k_pv(const unsigned short* __restrict__ P,
                                               const unsigned short* __restrict__ vpT,
                                               const float* __restrict__ inv_rs,
                                               float* __restrict__ out) {
  __shared__ __attribute__((aligned(16))) unsigned short AsAll[3 * A_TILE_USH];  // 96 KB
  __shared__ __attribute__((aligned(16))) unsigned short BsAll[3 * 64 * 64];     // 24 KB
  const int tid = threadIdx.x, lane = tid & 63, wid = tid >> 6;
  const int wm = wid >> 1, wn = wid & 1;
  const int mt = blockIdx.x, yt = blockIdx.y, b = blockIdx.z;
  const char* Ab = (const char*)(P + ((size_t)b * S_ + mt * 256) * S_);
  const char* Bb = (const char*)(vpT + ((size_t)b * E_ + yt * 64) * S_);
  f32x4 acc[4][2] = {};
  gemm_pipe<64, 2>(Ab, Bb, S_ * 2, S_ * 2, S_ / 64, AsAll, BsAll, tid, wm, wn, lane, acc);

#pragma unroll
  for (int m = 0; m < 4; ++m)
#pragma unroll
    for (int r = 0; r < 4; ++r) {
      const int grow = mt * 256 + wm * 64 + m * 16 + (lane >> 4) * 4 + r;
      const float inv = inv_rs[b * S_ + grow];
      const int gcol = yt * 64 + wn * 32 + (lane & 15);
      out[((size_t)b * S_ + grow) * E_ + gcol]      = acc[m][0][r] * inv;
      out[((size_t)b * S_ + grow) * E_ + gcol + 16] = acc[m][1][r] * inv;
    }
}

extern "C" void kernel_launch(void* const* d_in, const int* in_sizes, int n_in,
                              void* d_out, int out_size, void* d_ws, size_t ws_size,
                              hipStream_t stream) {
  const float* q = (const float*)d_in[0];
  const float* k = (const float*)d_in[1];
  const float* v = (const float*)d_in[2];
  const int* mask = (const int*)d_in[3];
  const float* W = (const float*)d_in[4];
  const float* bias = (const float*)d_in[5];
  float* out = (float*)d_out;
  char* ws = (char*)d_ws;

  // workspace layout (bytes)
  unsigned short* qp = (unsigned short*)(ws + 0);           //  24 MB
  unsigned short* kp = (unsigned short*)(ws + 25165824);    //  24 MB
  unsigned short* vpT = (unsigned short*)(ws + 50331648);   //  24 MB
  unsigned short* P = (unsigned short*)(ws + 75497472);     //  64 MiB
  unsigned short* vp_tmp = P;  // reused: consumed by k_vtrans before k_scores writes P
  float* rowsum = (float*)(ws + 142606336);                 // 16*B*S f32 = 1 MB
  float* inv_rs = (float*)(ws + 143654912);                 // B*S f32 = 64 KB
  (void)in_sizes; (void)n_in; (void)out_size; (void)ws_size;

  dim3 blk(256, 1, 1);
  dim3 blk2(512, 1, 1);
  k_proj<<<dim3(192, 6, 1), blk2, 0, stream>>>(q, k, v, W, bias, qp, kp, vp_tmp);
  k_vtrans<<<dim3(32, 12, 8), blk, 0, stream>>>(vp_tmp, vpT);
  k_scores<<<dim3(8, 16, 8), blk2, 0, stream>>>(qp, kp, mask, P, rowsum);
  k_invrs<<<dim3(64, 1, 1), blk, 0, stream>>>(rowsum, inv_rs);
  k_pv<<<dim3(8, 12, 8), blk2, 0, stream>>>(P, vpT, inv_rs, out);
}

// Round 5
// 337.456 us; speedup vs baseline: 1.1490x; 1.1490x over previous
//
#include <hip/hip_runtime.h>
#include <hip/hip_bf16.h>
#include <stdint.h>

#define B_ 8
#define S_ 2048
#define E_ 768

typedef __attribute__((ext_vector_type(4))) float f32x4;
typedef __attribute__((ext_vector_type(8))) short bf16x8;

// Pipelined GEMM core geometry: BM=256, BK=64, 512 thr (8 waves 4Mx2N)
#define A_TILE_USH (256 * 64)  // 32 KB

__device__ __forceinline__ unsigned pk2bf(float x, float y) {
  unsigned r;
  asm("v_cvt_pk_bf16_f32 %0, %1, %2" : "=v"(r) : "v"(x), "v"(y));
  return r;
}

__device__ __forceinline__ void gll16(const void* g, void* l) {
  __builtin_amdgcn_global_load_lds((const __attribute__((address_space(1))) void*)g,
                                   (__attribute__((address_space(3))) void*)l, 16, 0, 0);
}

// Stage K-tile kt (A: 256x64 bf16, B: BROWSx64 bf16) via global_load_lds.
// LDS dest linear; global SOURCE pre-swizzled with the reader's XOR (rule #21).
template <int BROWS>
__device__ __forceinline__ void stage_tile(const char* Ab, const char* Bb,
                                           int ldAb, int ldBb, int kt,
                                           unsigned short* As, unsigned short* Bs, int tid) {
#pragma unroll
  for (int i = 0; i < 4; ++i) {
    const unsigned lin = (unsigned)i * 8192u + (unsigned)tid * 16u;
    const unsigned row = lin >> 7, cb = lin & 127u;
    const unsigned cbs = cb ^ ((row & 7u) << 4);
    gll16(Ab + (size_t)row * ldAb + (size_t)kt * 128 + cbs, (char*)As + lin);
  }
#pragma unroll
  for (int i = 0; i < BROWS / 64; ++i) {
    const unsigned lin = (unsigned)i * 8192u + (unsigned)tid * 16u;
    const unsigned row = lin >> 7, cb = lin & 127u;
    const unsigned cbs = cb ^ ((row & 7u) << 4);
    gll16(Bb + (size_t)row * ldBb + (size_t)kt * 128 + cbs, (char*)Bs + lin);
  }
}

template <int NACC>
__device__ __forceinline__ void compute_tile(const unsigned short* As, const unsigned short* Bs,
                                             int wm, int wn, int lane, f32x4 (&acc)[4][NACC]) {
  bf16x8 af[4][2], bv[NACC][2];
#pragma unroll
  for (int m = 0; m < 4; ++m) {
    const int row = wm * 64 + m * 16 + (lane & 15);
#pragma unroll
    for (int ks = 0; ks < 2; ++ks) {
      const unsigned cb = ((unsigned)ks * 64u + (unsigned)(lane >> 4) * 16u) ^ (((unsigned)row & 7u) << 4);
      af[m][ks] = *reinterpret_cast<const bf16x8*>((const char*)As + row * 128 + cb);
    }
  }
#pragma unroll
  for (int n = 0; n < NACC; ++n) {
    const int row = wn * (NACC * 16) + n * 16 + (lane & 15);
#pragma unroll
    for (int ks = 0; ks < 2; ++ks) {
      const unsigned cb = ((unsigned)ks * 64u + (unsigned)(lane >> 4) * 16u) ^ (((unsigned)row & 7u) << 4);
      bv[n][ks] = *reinterpret_cast<const bf16x8*>((const char*)Bs + row * 128 + cb);
    }
  }
  __builtin_amdgcn_s_setprio(1);
#pragma unroll
  for (int ks = 0; ks < 2; ++ks)
#pragma unroll
    for (int m = 0; m < 4; ++m)
#pragma unroll
      for (int n = 0; n < NACC; ++n)
        acc[m][n] = __builtin_amdgcn_mfma_f32_16x16x32_bf16(af[m][ks], bv[n][ks], acc[m][n], 0, 0, 0);
  __builtin_amdgcn_s_setprio(0);
}

// 3-stage pipeline, one barrier per K-tile, counted vmcnt (= loads/tile).
template <int BROWS, int NACC>
__device__ __forceinline__ void gemm_pipe(const char* Ab, const char* Bb, int ldAb, int ldBb,
                                          int NT, unsigned short* AsAll, unsigned short* BsAll,
                                          int tid, int wm, int wn, int lane,
                                          f32x4 (&acc)[4][NACC]) {
  constexpr int BT = BROWS * 64;
  constexpr int L = 4 + BROWS / 64;
  stage_tile<BROWS>(Ab, Bb, ldAb, ldBb, 0, AsAll, BsAll, tid);
  stage_tile<BROWS>(Ab, Bb, ldAb, ldBb, 1, AsAll + A_TILE_USH, BsAll + BT, tid);
  if constexpr (L == 6) asm volatile("s_waitcnt vmcnt(6)" ::: "memory");
  else                  asm volatile("s_waitcnt vmcnt(5)" ::: "memory");
  __builtin_amdgcn_s_barrier();
  __builtin_amdgcn_sched_barrier(0);
  for (int kt = 0; kt < NT; ++kt) {
    const int bk = kt % 3;
    if (kt + 2 < NT) {
      const int bs = (kt + 2) % 3;
      stage_tile<BROWS>(Ab, Bb, ldAb, ldBb, kt + 2, AsAll + bs * A_TILE_USH, BsAll + bs * BT, tid);
    }
    compute_tile<NACC>(AsAll + bk * A_TILE_USH, BsAll + bk * BT, wm, wn, lane, acc);
    if (kt + 1 < NT) {
      if (kt + 2 < NT) {
        if constexpr (L == 6) asm volatile("s_waitcnt vmcnt(6) lgkmcnt(0)" ::: "memory");
        else                  asm volatile("s_waitcnt vmcnt(5) lgkmcnt(0)" ::: "memory");
      } else {
        asm volatile("s_waitcnt vmcnt(0) lgkmcnt(0)" ::: "memory");
      }
      __builtin_amdgcn_s_barrier();
      __builtin_amdgcn_sched_barrier(0);
    }
  }
}

// ---------------- K0: streaming f32 -> bf16 conversion (q,k,v,W) --------------------
__global__ __launch_bounds__(256) void k_cvt(const float* __restrict__ q,
                                             const float* __restrict__ k,
                                             const float* __restrict__ v,
                                             const float* __restrict__ W,
                                             unsigned short* __restrict__ qb,
                                             unsigned short* __restrict__ kb,
                                             unsigned short* __restrict__ vb,
                                             unsigned short* __restrict__ Wb) {
  const int y = blockIdx.y;
  const float* src = (y == 0) ? q : (y == 1) ? k : (y == 2) ? v : W;
  unsigned short* dst = (y == 0) ? qb : (y == 1) ? kb : (y == 2) ? vb : Wb;
  const int n4 = (y < 3) ? (B_ * S_ * E_ / 4) : (E_ * E_ / 4);
  const int stride = gridDim.x * 256;
  for (int i = blockIdx.x * 256 + threadIdx.x; i < n4; i += stride) {
    float4 f = reinterpret_cast<const float4*>(src)[i];
    uint2 p;
    p.x = pk2bf(f.x, f.y);
    p.y = pk2bf(f.z, f.w);
    reinterpret_cast<uint2*>(dst)[i] = p;
  }
}

// ---------------- K1: projection GEMM  O = Xb @ Wb^T + b  (bf16 in/out) -------------
__global__ __launch_bounds__(512, 2) void k_projb(const unsigned short* __restrict__ Xb,
                                                  const unsigned short* __restrict__ Wb,
                                                  const float* __restrict__ bias,
                                                  unsigned short* __restrict__ qp,
                                                  unsigned short* __restrict__ kp,
                                                  unsigned short* __restrict__ vp) {
  __shared__ __attribute__((aligned(16))) unsigned short AsAll[3 * A_TILE_USH];  // 96 KB
  __shared__ __attribute__((aligned(16))) unsigned short BsAll[3 * 128 * 64];    // 48 KB
  const int tid = threadIdx.x, lane = tid & 63, wid = tid >> 6;
  const int wm = wid >> 1, wn = wid & 1;
  const int r0 = blockIdx.x * 256, c0 = blockIdx.y * 128, z = blockIdx.z;
  const unsigned short* X = Xb + (size_t)z * (B_ * S_ * E_);
  unsigned short* O = (z == 0) ? qp : ((z == 1) ? kp : vp);

  const char* Ab = (const char*)(X + (size_t)r0 * E_);
  const char* Bb = (const char*)(Wb + (size_t)c0 * E_);
  f32x4 acc[4][4] = {};
  gemm_pipe<128, 4>(Ab, Bb, E_ * 2, E_ * 2, E_ / 64, AsAll, BsAll, tid, wm, wn, lane, acc);

  float bcol[4];
#pragma unroll
  for (int n = 0; n < 4; ++n) bcol[n] = bias[c0 + wn * 64 + n * 16 + (lane & 15)];
#pragma unroll
  for (int m = 0; m < 4; ++m)
#pragma unroll
    for (int r = 0; r < 4; ++r) {
      const int row = r0 + wm * 64 + m * 16 + (lane >> 4) * 4 + r;
      const int colb = c0 + wn * 64 + (lane & 15);
      unsigned pkA = pk2bf(acc[m][0][r] + bcol[0], acc[m][1][r] + bcol[1]);
      unsigned pkB = pk2bf(acc[m][2][r] + bcol[2], acc[m][3][r] + bcol[3]);
      O[(size_t)row * E_ + colb]      = (unsigned short)pkA;
      O[(size_t)row * E_ + colb + 16] = (unsigned short)(pkA >> 16);
      O[(size_t)row * E_ + colb + 32] = (unsigned short)pkB;
      O[(size_t)row * E_ + colb + 48] = (unsigned short)(pkB >> 16);
    }
}

// ---------------- K1b: transpose vp [B*S][E] -> vpT [B][E][S] ------------------------
__global__ __launch_bounds__(256) void k_vtrans(const unsigned short* __restrict__ vp,
                                                unsigned short* __restrict__ vpT) {
  __shared__ __attribute__((aligned(16))) unsigned short t[64][72];
  const int tid = threadIdx.x;
  const int st = blockIdx.x;
  const int ot = blockIdx.y;
  const int b = blockIdx.z;
#pragma unroll
  for (int i = 0; i < 2; ++i) {
    int f = i * 256 + tid;
    int s = f >> 3, c8 = f & 7;
    uint4 vv = *reinterpret_cast<const uint4*>(
        &vp[((size_t)b * S_ + st * 64 + s) * E_ + ot * 64 + c8 * 8]);
    *reinterpret_cast<uint4*>(&t[s][c8 * 8]) = vv;
  }
  __syncthreads();
  const int o = tid >> 2;
  const int sb = (tid & 3) * 16;
  unsigned p[8];
#pragma unroll
  for (int j = 0; j < 8; ++j)
    p[j] = (unsigned)t[sb + 2 * j][o] | ((unsigned)t[sb + 2 * j + 1][o] << 16);
  uint4 w0 = make_uint4(p[0], p[1], p[2], p[3]);
  uint4 w1 = make_uint4(p[4], p[5], p[6], p[7]);
  size_t ob = ((size_t)b * E_ + ot * 64 + o) * S_ + st * 64 + sb;
  *reinterpret_cast<uint4*>(&vpT[ob]) = w0;
  *reinterpret_cast<uint4*>(&vpT[ob + 8]) = w1;
}

// ---------------- K2: scores tile GEMM + mask + exp (unnormalized) + rowsum ---------
__global__ __launch_bounds__(512, 2) void k_scores(const unsigned short* __restrict__ qp,
                                                   const unsigned short* __restrict__ kp,
                                                   const int* __restrict__ mask,
                                                   unsigned short* __restrict__ P,
                                                   float* __restrict__ rowsum) {
  __shared__ __attribute__((aligned(16))) unsigned short AsAll[3 * A_TILE_USH];  // 96 KB
  __shared__ __attribute__((aligned(16))) unsigned short BsAll[3 * 128 * 64];    // 48 KB
  __shared__ float rlds[256][2];
  const int tid = threadIdx.x, lane = tid & 63, wid = tid >> 6;
  const int wm = wid >> 1, wn = wid & 1;
  const int qt = blockIdx.x, yt = blockIdx.y, b = blockIdx.z;
  const char* Ab = (const char*)(qp + ((size_t)b * S_ + qt * 256) * E_);
  const char* Bb = (const char*)(kp + ((size_t)b * S_ + yt * 128) * E_);
  f32x4 acc[4][4] = {};
  gemm_pipe<128, 4>(Ab, Bb, E_ * 2, E_ * 2, E_ / 64, AsAll, BsAll, tid, wm, wn, lane, acc);

  const float SC = (float)(1.4426950408889634 / 27.712812921102035);  // log2(e)/sqrt(768)
  float rs[4][4];
#pragma unroll
  for (int m = 0; m < 4; ++m)
#pragma unroll
    for (int r = 0; r < 4; ++r) {
      const int grow = qt * 256 + wm * 64 + m * 16 + (lane >> 4) * 4 + r;
      const size_t rowoff = ((size_t)b * S_ + grow) * S_;
      const int cbase = yt * 128 + wn * 64 + (lane & 15);
      const int mk0 = mask[rowoff + cbase];
      const int mk1 = mask[rowoff + cbase + 16];
      const int mk2 = mask[rowoff + cbase + 32];
      const int mk3 = mask[rowoff + cbase + 48];
      float p0 = (mk0 == 1) ? 0.f : __builtin_amdgcn_exp2f(acc[m][0][r] * SC);
      float p1 = (mk1 == 1) ? 0.f : __builtin_amdgcn_exp2f(acc[m][1][r] * SC);
      float p2 = (mk2 == 1) ? 0.f : __builtin_amdgcn_exp2f(acc[m][2][r] * SC);
      float p3 = (mk3 == 1) ? 0.f : __builtin_amdgcn_exp2f(acc[m][3][r] * SC);
      unsigned pkA = pk2bf(p0, p1);
      unsigned pkB = pk2bf(p2, p3);
      P[rowoff + cbase]      = (unsigned short)pkA;
      P[rowoff + cbase + 16] = (unsigned short)(pkA >> 16);
      P[rowoff + cbase + 32] = (unsigned short)pkB;
      P[rowoff + cbase + 48] = (unsigned short)(pkB >> 16);
      rs[m][r] = (p0 + p1) + (p2 + p3);
    }

#pragma unroll
  for (int m = 0; m < 4; ++m)
#pragma unroll
    for (int r = 0; r < 4; ++r) {
      float vsum = rs[m][r];
      vsum += __shfl_xor(vsum, 1);
      vsum += __shfl_xor(vsum, 2);
      vsum += __shfl_xor(vsum, 4);
      vsum += __shfl_xor(vsum, 8);
      if ((lane & 15) == 0) rlds[wm * 64 + m * 16 + (lane >> 4) * 4 + r][wn] = vsum;
    }
  __syncthreads();
  if (tid < 256) {
    rowsum[(size_t)yt * (B_ * S_) + (size_t)b * S_ + qt * 256 + tid] =
        rlds[tid][0] + rlds[tid][1];
  }
}

// ---------------- K2b: inv_rs = 1 / sum_yt rowsum -----------------------------------
__global__ __launch_bounds__(256) void k_invrs(const float* __restrict__ rowsum,
                                               float* __restrict__ inv_rs) {
  int i = blockIdx.x * 256 + threadIdx.x;
  float t = 0.f;
#pragma unroll
  for (int g = 0; g < 16; ++g) t += rowsum[(size_t)g * (B_ * S_) + i];
  inv_rs[i] = 1.0f / t;
}

// ---------------- K3: out = (P @ vpT^T) * inv_rs  (f32 out), BN=64 ------------------
__global__ __launch_bounds__(512, 2) void k_pv(const unsigned short* __restrict__ P,
                                               const unsigned short* __restrict__ vpT,
                                               const float* __restrict__ inv_rs,
                                               float* __restrict__ out) {
  __shared__ __attribute__((aligned(16))) unsigned short AsAll[3 * A_TILE_USH];  // 96 KB
  __shared__ __attribute__((aligned(16))) unsigned short BsAll[3 * 64 * 64];     // 24 KB
  const int tid = threadIdx.x, lane = tid & 63, wid = tid >> 6;
  const int wm = wid >> 1, wn = wid & 1;
  const int mt = blockIdx.x, yt = blockIdx.y, b = blockIdx.z;
  const char* Ab = (const char*)(P + ((size_t)b * S_ + mt * 256) * S_);
  const char* Bb = (const char*)(vpT + ((size_t)b * E_ + yt * 64) * S_);
  f32x4 acc[4][2] = {};
  gemm_pipe<64, 2>(Ab, Bb, S_ * 2, S_ * 2, S_ / 64, AsAll, BsAll, tid, wm, wn, lane, acc);

#pragma unroll
  for (int m = 0; m < 4; ++m)
#pragma unroll
    for (int r = 0; r < 4; ++r) {
      const int grow = mt * 256 + wm * 64 + m * 16 + (lane >> 4) * 4 + r;
      const float inv = inv_rs[b * S_ + grow];
      const int gcol = yt * 64 + wn * 32 + (lane & 15);
      out[((size_t)b * S_ + grow) * E_ + gcol]      = acc[m][0][r] * inv;
      out[((size_t)b * S_ + grow) * E_ + gcol + 16] = acc[m][1][r] * inv;
    }
}

extern "C" void kernel_launch(void* const* d_in, const int* in_sizes, int n_in,
                              void* d_out, int out_size, void* d_ws, size_t ws_size,
                              hipStream_t stream) {
  const float* q = (const float*)d_in[0];
  const float* k = (const float*)d_in[1];
  const float* v = (const float*)d_in[2];
  const int* mask = (const int*)d_in[3];
  const float* W = (const float*)d_in[4];
  const float* bias = (const float*)d_in[5];
  float* out = (float*)d_out;
  char* ws = (char*)d_ws;

  // workspace layout (bytes); high-water 152174592 B (~145 MB)
  unsigned short* qb = (unsigned short*)(ws + 0);          // 3x24MB, contiguous q,k,v
  unsigned short* kb = (unsigned short*)(ws + 25165824);
  unsigned short* vb = (unsigned short*)(ws + 50331648);
  unsigned short* Wb = (unsigned short*)(ws + 75497472);   // 1.18 MB, dead after k_projb
  unsigned short* qp = (unsigned short*)(ws + 76677120);   // 24 MB
  unsigned short* kp = (unsigned short*)(ws + 101842944);  // 24 MB
  unsigned short* vpT = (unsigned short*)(ws + 127008768); // 24 MB
  // aliases over dead regions:
  unsigned short* P = (unsigned short*)(ws + 0);           // 64 MiB over dead qb/kb/vb
  float* rowsum = (float*)(ws + 75497472);                 // 1 MB over dead Wb
  float* inv_rs = (float*)(ws + 76546048);                 // 64 KB, still inside Wb slot
  unsigned short* vp_tmp = (unsigned short*)d_out;         // 24 MB scratch; k_pv overwrites
  (void)in_sizes; (void)n_in; (void)out_size; (void)ws_size;

  dim3 blk(256, 1, 1);
  dim3 blk2(512, 1, 1);
  k_cvt<<<dim3(512, 4, 1), blk, 0, stream>>>(q, k, v, W, qb, kb, vb, Wb);
  k_projb<<<dim3(64, 6, 3), blk2, 0, stream>>>(qb, Wb, bias, qp, kp, vp_tmp);
  k_vtrans<<<dim3(32, 12, 8), blk, 0, stream>>>(vp_tmp, vpT);
  k_scores<<<dim3(8, 16, 8), blk2, 0, stream>>>(qp, kp, mask, P, rowsum);
  k_invrs<<<dim3(64, 1, 1), blk, 0, stream>>>(rowsum, inv_rs);
  k_pv<<<dim3(8, 12, 8), blk2, 0, stream>>>(P, vpT, inv_rs, out);
}